// Round 3
// baseline (269.552 us; speedup 1.0000x reference)
//
#include <hip/hip_runtime.h>
#include <hip/hip_bf16.h>

#define B_  8
#define H_  512
#define L_  2048
#define D2_ 32

typedef __attribute__((ext_vector_type(8))) short short8;   // 8 bf16 (4 VGPRs)
typedef __attribute__((ext_vector_type(4))) float float4v;  // 4 fp32 acc

__device__ __forceinline__ float gelu_exact(float x) {
    return 0.5f * x * (1.0f + erff(x * 0.70710678118654752f));
}

__device__ __forceinline__ unsigned pack_bf16x2(float x, float y) {
    __hip_bfloat162 p = __float22bfloat162_rn(make_float2(x, y));
    return *(unsigned*)&p;
}
__device__ __forceinline__ float2 unpack_bf16x2(unsigned v) {
    __hip_bfloat162 p = *(__hip_bfloat162*)&v;
    return __bfloat1622float2(p);
}

__device__ __forceinline__ void load_lds16(const void* g, void* l) {
    __builtin_amdgcn_global_load_lds((const __attribute__((address_space(1))) unsigned int*)g,
                                     (__attribute__((address_space(3))) unsigned int*)l, 16, 0, 0);
}

// ---------------- kernel 0: cast W (512x512 f32) -> bf16 ----------------
__global__ void cast_w_kernel(const float* __restrict__ W, __hip_bfloat16* __restrict__ Wb) {
    int tid = blockIdx.x * 256 + threadIdx.x;
    Wb[tid] = __float2bfloat16(W[tid]);
}

// ---------------- kernel 1: f[h,l], k0[h,l] ----------------
__global__ void fk_kernel(const float* __restrict__ a, const float* __restrict__ th,
                          const float* __restrict__ bb, const float* __restrict__ cc,
                          const float* __restrict__ x0, float2* __restrict__ FK) {
    int tid = blockIdx.x * 256 + threadIdx.x;   // H_*L_ threads
    int h = tid >> 11;
    int l = tid & (L_ - 1);
    const float T = 1.0f / (float)(L_ - 1);
    float z = T * (float)l;
    float facc = 0.f, kacc = 0.f;
    #pragma unroll
    for (int d = 0; d < D2_; ++d) {
        float av = a[h * D2_ + d];
        float tv = th[h * D2_ + d];
        float e = __expf(-fabsf(av) * z) * __cosf(tv * z);
        facc = fmaf(bb[h * D2_ + d] * cc[h * D2_ + d], e, facc);
        kacc = fmaf(cc[h * D2_ + d] * x0[h * D2_ + d], e, kacc);
    }
    FK[tid] = make_float2(2.0f * T * facc, 2.0f * kacc);
}

// ---------------- Pass A: chunk-local scans from zero state (E as bf16x2) ----------------
template <int NC, int LC>
__global__ __launch_bounds__(256) void scan_chunk_kernel(
        const float* __restrict__ u, const float* __restrict__ a,
        const float* __restrict__ th, unsigned* __restrict__ E) {
    int tid = blockIdx.x * 256 + threadIdx.x;   // B_*H_*D2_*NC threads
    int d  = tid & (D2_ - 1);
    int c  = (tid >> 5) & (NC - 1);
    int bh = tid / (D2_ * NC);
    int h  = bh & (H_ - 1);
    const float T = 1.0f / (float)(L_ - 1);
    float aa  = -fabsf(a[h * D2_ + d]);
    float ea  = __expf(aa * T);
    float tT  = th[h * D2_ + d] * T;
    float wr  = ea * __cosf(tT);
    float wi  = ea * __sinf(tT);
    const float* ur = u + (size_t)bh * L_ + c * LC;
    float sr = 0.f, si = 0.f;
    #pragma unroll 8
    for (int i = 0; i < LC; ++i) {
        float ul = ur[i];
        float nr = fmaf(sr, wr, fmaf(-si, wi, ul));
        float ni = fmaf(sr, wi, si * wr);
        sr = nr; si = ni;
    }
    E[((size_t)bh * NC + c) * D2_ + d] = pack_bf16x2(sr, si);
}

// ---------------- combine: in-place E[c] -> carry ENTERING chunk c ----------------
template <int NC, int LC>
__global__ __launch_bounds__(256) void combine_kernel(
        const float* __restrict__ a, const float* __restrict__ th,
        unsigned* __restrict__ E) {
    int tid = blockIdx.x * 256 + threadIdx.x;   // B_*H_*D2_ = 131072 threads
    int d  = tid & (D2_ - 1);
    int bh = tid >> 5;
    int h  = bh & (H_ - 1);
    const float T = 1.0f / (float)(L_ - 1);
    float aa  = -fabsf(a[h * D2_ + d]);
    float eC  = __expf(aa * T * (float)LC);
    float tC  = th[h * D2_ + d] * T * (float)LC;
    float Wr  = eC * __cosf(tC);
    float Wi  = eC * __sinf(tC);
    float sr = 0.f, si = 0.f;
    for (int c = 0; c < NC; ++c) {
        size_t idx = ((size_t)bh * NC + c) * D2_ + d;
        float2 e = unpack_bf16x2(E[idx]);
        E[idx] = pack_bf16x2(sr, si);            // carry entering chunk c
        float nr = fmaf(sr, Wr, fmaf(-si, Wi, e.x));
        float ni = fmaf(sr, Wi, fmaf(si, Wr, e.y));
        sr = nr; si = ni;
    }
}

// ---------------- Pass B: full scan per chunk, fused epilogue ----------------
template <int NC, int LC>
__global__ __launch_bounds__(256) void scan_full_kernel(
        const float* __restrict__ u, const float* __restrict__ a,
        const float* __restrict__ th, const float* __restrict__ bb,
        const float* __restrict__ cc, const float* __restrict__ Dp,
        const float2* __restrict__ FK, const unsigned* __restrict__ E,
        __hip_bfloat16* __restrict__ yT) {
    int c = blockIdx.x;                       // 0..NC-1
    int b = blockIdx.z;                       // 0..7
    int h = blockIdx.y * 256 + threadIdx.x;   // 0..511
    int bh = b * H_ + h;
    const float T = 1.0f / (float)(L_ - 1);

    float wr[D2_], wi[D2_], q[D2_], sr[D2_], si[D2_];
    float qsum = 0.f;
    #pragma unroll
    for (int d = 0; d < D2_; ++d) {
        float aa = -fabsf(a[h * D2_ + d]);
        float ea = __expf(aa * T);
        float tT = th[h * D2_ + d] * T;
        wr[d] = ea * __cosf(tT);
        wi[d] = ea * __sinf(tT);
        q[d]  = bb[h * D2_ + d] * cc[h * D2_ + d];
        qsum += q[d];
    }
    float f0 = 2.0f * T * qsum;               // f[h,0]

    #pragma unroll
    for (int d = 0; d < D2_; ++d) {
        float2 s = unpack_bf16x2(E[((size_t)bh * NC + c) * D2_ + d]);
        sr[d] = s.x; si[d] = s.y;
    }

    float u0 = u[(size_t)bh * L_];
    float Dh = Dp[h];
    const float*  ur  = u  + (size_t)bh * L_ + c * LC;
    const float2* fkr = FK + (size_t)h  * L_ + c * LC;
    __hip_bfloat16* yr = yT + ((size_t)b * L_ + c * LC) * H_ + h;

    for (int i = 0; i < LC; ++i) {
        float ul = ur[i];
        float2 fk = fkr[i];
        float dta[4] = {0.f, 0.f, 0.f, 0.f};
        #pragma unroll
        for (int d = 0; d < D2_; ++d) {
            float nr = fmaf(sr[d], wr[d], fmaf(-si[d], wi[d], ul));
            float ni = fmaf(sr[d], wi[d], si[d] * wr[d]);
            sr[d] = nr; si[d] = ni;
            dta[d & 3] = fmaf(q[d], nr, dta[d & 3]);
        }
        float dot = (dta[0] + dta[1]) + (dta[2] + dta[3]);
        float y = fmaf(2.0f * T, dot, fk.y)           // conv + k0
                  - 0.5f * (f0 * ul + fk.x * u0)      // trapezoid correction
                  + Dh * ul;                          // skip D*u
        yr[(size_t)i * H_] = __float2bfloat16(gelu_exact(y));
    }
}

// ---------------- gemm: out[b,h,l] = sum_f W[h,f] * yT[b,l,f] + bias[h] ----------------
__global__ __launch_bounds__(256) void gemm_kernel(
        const __hip_bfloat16* __restrict__ Wb, const __hip_bfloat16* __restrict__ yT,
        const float* __restrict__ bias, float* __restrict__ out) {
    __shared__ __align__(16) short As[128 * 32];
    __shared__ __align__(16) short Bs[128 * 32];
    int l0 = blockIdx.x * 128;      // N tile
    int h0 = blockIdx.y * 128;      // M tile
    int b  = blockIdx.z;
    int t    = threadIdx.x;
    int lane = t & 63, wave = t >> 6;
    int m_off = (wave >> 1) * 64, n_off = (wave & 1) * 64;
    int quad = lane >> 4, ln = lane & 15;

    float4v acc[4][4];
    #pragma unroll
    for (int mt = 0; mt < 4; ++mt)
        #pragma unroll
        for (int nt = 0; nt < 4; ++nt)
            acc[mt][nt] = (float4v){0.f, 0.f, 0.f, 0.f};

    const short* Wg = (const short*)Wb;
    const short* Yg = (const short*)(yT + (size_t)b * L_ * H_);

    int r  = t >> 2;      // 0..63
    int qd = t & 3;       // 16B chunk within 64B row

    for (int kt = 0; kt < 16; ++kt) {
        int k0 = kt * 32;
        // async global->LDS staging, 16B/lane, LDS dest = base + t*16B (contiguous per wave)
        load_lds16(Wg + (h0 + r)      * 512 + k0 + qd * 8, &As[t * 8]);
        load_lds16(Wg + (h0 + r + 64) * 512 + k0 + qd * 8, &As[(t + 256) * 8]);
        load_lds16(Yg + (size_t)(l0 + r)      * 512 + k0 + qd * 8, &Bs[t * 8]);
        load_lds16(Yg + (size_t)(l0 + r + 64) * 512 + k0 + qd * 8, &Bs[(t + 256) * 8]);
        __syncthreads();

        short8 af[4], bf[4];
        #pragma unroll
        for (int mt = 0; mt < 4; ++mt)
            af[mt] = *(const short8*)&As[(m_off + mt * 16 + ln) * 32 + quad * 8];
        #pragma unroll
        for (int nt = 0; nt < 4; ++nt)
            bf[nt] = *(const short8*)&Bs[(n_off + nt * 16 + ln) * 32 + quad * 8];
        #pragma unroll
        for (int mt = 0; mt < 4; ++mt)
            #pragma unroll
            for (int nt = 0; nt < 4; ++nt)
                acc[mt][nt] = __builtin_amdgcn_mfma_f32_16x16x32_bf16(
                    af[mt], bf[nt], acc[mt][nt], 0, 0, 0);
        __syncthreads();
    }

    #pragma unroll
    for (int mt = 0; mt < 4; ++mt) {
        #pragma unroll
        for (int nt = 0; nt < 4; ++nt) {
            int hh = h0 + m_off + mt * 16 + quad * 4;
            int ll = l0 + n_off + nt * 16 + ln;
            #pragma unroll
            for (int r2 = 0; r2 < 4; ++r2)
                out[((size_t)(b * H_ + hh + r2)) * L_ + ll] = acc[mt][nt][r2] + bias[hh + r2];
        }
    }
}

template <int NC, int LC>
static void launch_pipeline(const float* u, const float* a, const float* th,
                            const float* bb, const float* cc, const float* x0,
                            const float* Dp, const float* W, const float* bias,
                            float* out, char* ws, size_t e_off, size_t yt_off,
                            size_t wb_off, hipStream_t stream) {
    float2*   FK = (float2*)ws;
    unsigned* E  = (unsigned*)(ws + e_off);
    __hip_bfloat16* yT = (__hip_bfloat16*)(ws + yt_off);
    __hip_bfloat16* Wb = (__hip_bfloat16*)(ws + wb_off);
    hipLaunchKernelGGL(cast_w_kernel, dim3(1024), dim3(256), 0, stream, W, Wb);
    hipLaunchKernelGGL(fk_kernel, dim3(4096), dim3(256), 0, stream, a, th, bb, cc, x0, FK);
    hipLaunchKernelGGL((scan_chunk_kernel<NC, LC>), dim3(B_ * H_ * D2_ * NC / 256), dim3(256),
                       0, stream, u, a, th, E);
    hipLaunchKernelGGL((combine_kernel<NC, LC>), dim3(512), dim3(256), 0, stream, a, th, E);
    hipLaunchKernelGGL((scan_full_kernel<NC, LC>), dim3(NC, 2, 8), dim3(256), 0, stream,
                       u, a, th, bb, cc, Dp, FK, E, yT);
    hipLaunchKernelGGL(gemm_kernel, dim3(16, 4, 8), dim3(256), 0, stream, Wb, yT, bias, out);
}

extern "C" void kernel_launch(void* const* d_in, const int* in_sizes, int n_in,
                              void* d_out, int out_size, void* d_ws, size_t ws_size,
                              hipStream_t stream) {
    const float* u    = (const float*)d_in[0];
    const float* a    = (const float*)d_in[1];
    const float* th   = (const float*)d_in[2];
    const float* bb   = (const float*)d_in[3];
    const float* cc   = (const float*)d_in[4];
    const float* x0   = (const float*)d_in[5];
    const float* Dp   = (const float*)d_in[6];
    const float* W    = (const float*)d_in[7];
    const float* bias = (const float*)d_in[8];
    float* out = (float*)d_out;
    char* ws = (char*)d_ws;

    if (ws_size >= (57ull << 20)) {
        // FK 8 MiB | E 32 MiB @8M | yT 16 MiB @40M | Wb @56M   (56.5 MiB total)
        launch_pipeline<64, 32>(u, a, th, bb, cc, x0, Dp, W, bias, out, ws,
                                8ull << 20, 40ull << 20, 56ull << 20, stream);
    } else {
        // FK 8 MiB | E 8 MiB @8M | yT 16 MiB @16M | Wb @32M    (32.5 MiB total)
        launch_pipeline<16, 128>(u, a, th, bb, cc, x0, Dp, W, bias, out, ws,
                                 8ull << 20, 16ull << 20, 32ull << 20, stream);
    }
}